// Round 1
// baseline (716.080 us; speedup 1.0000x reference)
//
#include <hip/hip_runtime.h>
#include <math.h>

// Problem constants (from reference)
#define NNODE  200000
#define DIM    64
#define NF     4
#define NLAYER 2
#define KK     32
#define BB     1024

// One block per (tower, b, layer): 2*1024*2 = 4096 blocks, 256 threads.
// wave (threadIdx.x>>6) = factor f; lane = hidden dim d.
// W1 column d held in 128 VGPRs; gathered x rows broadcast via scalar loads
// (indices forced uniform with readfirstlane).
__global__ __launch_bounds__(256, 2) void kgat_fused(
    const float* __restrict__ node_emb,
    const float* __restrict__ W1,
    const float* __restrict__ b1,
    const float* __restrict__ W2,
    const float* __restrict__ b2,
    const int*   __restrict__ users,
    const int*   __restrict__ items,
    const int*   __restrict__ users_triple,
    const int*   __restrict__ items_triple,
    float*       __restrict__ out)
{
    const int bid   = blockIdx.x;          // 0..4095
    const int tower = bid >> 11;           // 0 = users, 1 = items
    const int b     = (bid >> 1) & 1023;
    const int layer = bid & 1;
    const int f     = __builtin_amdgcn_readfirstlane(threadIdx.x >> 6); // wave id = factor
    const int lane  = threadIdx.x & 63;    // hidden dim d

    const int* __restrict__ triple = tower ? items_triple : users_triple;
    const int* __restrict__ idxarr = tower ? items : users;

    // W1 column `lane` into registers: w1r[i] = W1[i][lane]
    float w1r[128];
#pragma unroll
    for (int i = 0; i < 128; ++i) w1r[i] = W1[i * 64 + lane];
    const float w2r = W2[lane];
    const float b1r = b1[lane];
    const float b2s = b2[0];

    // triple layout: (B, 3, NLAYER, KK); channel 0 = h, 2 = t
    const int hbase = ((b * 3 + 0) * NLAYER + layer) * KK;
    const int tbase = ((b * 3 + 2) * NLAYER + layer) * KK;

    // lane k (k<32) will hold logit for edge k
    float logit_v = -INFINITY;

#pragma unroll 1
    for (int k = 0; k < KK; ++k) {
        const int hidx = __builtin_amdgcn_readfirstlane(triple[hbase + k]);
        const int tidx = __builtin_amdgcn_readfirstlane(triple[tbase + k]);
        const float* __restrict__ hp = node_emb + ((size_t)hidx * NF + f) * DIM;
        const float* __restrict__ tp = node_emb + ((size_t)tidx * NF + f) * DIM;

        // hid_d = relu(b1[d] + sum_i h[i]*W1[i][d] + sum_i t[i]*W1[64+i][d])
        float a0 = 0.f, a1 = 0.f, a2 = 0.f, a3 = 0.f;
#pragma unroll
        for (int i = 0; i < 64; i += 4) {
            a0 += hp[i + 0] * w1r[i + 0];
            a1 += hp[i + 1] * w1r[i + 1];
            a2 += hp[i + 2] * w1r[i + 2];
            a3 += hp[i + 3] * w1r[i + 3];
        }
#pragma unroll
        for (int i = 0; i < 64; i += 4) {
            a0 += tp[i + 0] * w1r[64 + i + 0];
            a1 += tp[i + 1] * w1r[64 + i + 1];
            a2 += tp[i + 2] * w1r[64 + i + 2];
            a3 += tp[i + 3] * w1r[64 + i + 3];
        }
        float hid = fmaxf((a0 + a1) + (a2 + a3) + b1r, 0.f);

        // logit = sum_d hid_d * W2[d] + b2  (butterfly over all 64 lanes)
        float prod = hid * w2r;
#pragma unroll
        for (int off = 32; off; off >>= 1)
            prod += __shfl_xor(prod, off, 64);
        const float logit = prod + b2s;
        logit_v = (lane == k) ? logit : logit_v;
    }

    // softmax over k (lanes 0..31 hold the 32 logits)
    float m = logit_v;
#pragma unroll
    for (int off = 16; off; off >>= 1)
        m = fmaxf(m, __shfl_xor(m, off, 32));
    const float e = (lane < 32) ? __expf(logit_v - m) : 0.f;
    float s = e;
#pragma unroll
    for (int off = 16; off; off >>= 1)
        s += __shfl_xor(s, off, 32);
    const float w_v = e / s;   // valid in lanes 0..31

    // out[tower][1+layer][b][f][d] = sum_k w_k * t_emb[k][f][d]
    float oacc = 0.f;
#pragma unroll 1
    for (int k = 0; k < KK; ++k) {
        const float wk = __shfl(w_v, k, 64);
        const int tidx = __builtin_amdgcn_readfirstlane(triple[tbase + k]);
        const float* __restrict__ tp = node_emb + ((size_t)tidx * NF + f) * DIM;
        oacc += wk * tp[lane];
    }
    out[((size_t)(tower * 3 + 1 + layer) * BB + b) * (NF * DIM) + f * DIM + lane] = oacc;

    // origin row: out[tower][0][b][f][d] = node_emb[idx[b]][f][d]
    if (layer == 0) {
        const int oid = __builtin_amdgcn_readfirstlane(idxarr[b]);
        out[((size_t)(tower * 3 + 0) * BB + b) * (NF * DIM) + f * DIM + lane] =
            node_emb[((size_t)oid * NF + f) * DIM + lane];
    }
}

extern "C" void kernel_launch(void* const* d_in, const int* in_sizes, int n_in,
                              void* d_out, int out_size, void* d_ws, size_t ws_size,
                              hipStream_t stream) {
    const float* node_emb     = (const float*)d_in[0];
    // d_in[1] = relation_emb — unused by the reference computation
    const float* W1           = (const float*)d_in[2];
    const float* b1           = (const float*)d_in[3];
    const float* W2           = (const float*)d_in[4];
    const float* b2           = (const float*)d_in[5];
    const int*   users        = (const int*)d_in[6];
    const int*   items        = (const int*)d_in[7];
    const int*   users_triple = (const int*)d_in[8];
    const int*   items_triple = (const int*)d_in[9];
    float* out = (float*)d_out;

    dim3 grid(2 * BB * NLAYER);   // 4096
    dim3 block(256);
    hipLaunchKernelGGL(kgat_fused, grid, block, 0, stream,
                       node_emb, W1, b1, W2, b2,
                       users, items, users_triple, items_triple, out);
}

// Round 2
// 302.867 us; speedup vs baseline: 2.3643x; 2.3643x over previous
//
#include <hip/hip_runtime.h>
#include <hip/hip_bf16.h>
#include <math.h>

#define NNODE  200000
#define DIM    64
#define NF     4
#define NLAYER 2
#define KK     32
#define BB     1024

typedef __bf16 bf16x8 __attribute__((ext_vector_type(8)));
typedef __bf16 bf16x4 __attribute__((ext_vector_type(4)));
typedef float  f32x4  __attribute__((ext_vector_type(4)));

// X row stride in bf16 elements: 128 + 8 pad -> 272 B (16B-aligned, 2-way-only
// bank aliasing for the strided b128 fragment reads; 2-way is free per m136).
#define XSTRIDE 136

// Kernel 1: W1 (128x64 f32, row-major) -> W1T bf16 (64 x 128): w1t[d*128+i] = W1[i][d]
__global__ void prep_w1t(const float* __restrict__ W1, __bf16* __restrict__ w1t) {
    int j = blockIdx.x * 256 + threadIdx.x;   // 0..8191
    int d = j >> 7, i = j & 127;
    w1t[j] = (__bf16)W1[i * 64 + d];
}

// One block per (tower, b, layer). 256 threads = 4 waves; wave w = factor f.
// Per block: X = (128 rows (f*32+k) x 128 cols [h||t]) @ W1 (128x64) via MFMA.
__global__ __launch_bounds__(256, 2) void kgat_mfma(
    const float* __restrict__ node_emb,
    const __bf16* __restrict__ w1t,
    const float* __restrict__ b1,
    const float* __restrict__ W2,
    const int*   __restrict__ users,
    const int*   __restrict__ items,
    const int*   __restrict__ users_triple,
    const int*   __restrict__ items_triple,
    float*       __restrict__ out)
{
    __shared__ __bf16 Xs[128 * XSTRIDE];   // ~34 KB
    __shared__ float  logitS[128];

    const int bid   = blockIdx.x;          // 0..4095
    const int tower = bid >> 11;
    const int b     = (bid >> 1) & 1023;
    const int layer = bid & 1;
    const int tid   = threadIdx.x;
    const int w     = tid >> 6;            // wave id = factor
    const int lane  = tid & 63;
    const int m16   = lane & 15;
    const int quad  = lane >> 4;

    const int* __restrict__ triple = tower ? items_triple : users_triple;
    const int* __restrict__ idxarr = tower ? items : users;

    const int hbase = ((b * 3 + 0) * NLAYER + layer) * KK;
    const int tbase = ((b * 3 + 2) * NLAYER + layer) * KK;

    // ---- B fragments (W1): B[k][n], n = nt*16 + m16, k = kt*32 + quad*8 + j ----
    // Loaded once from pre-transposed bf16 W1T in global (L2-hot). 64 VGPRs.
    bf16x8 Bf[4][4];
#pragma unroll
    for (int nt = 0; nt < 4; ++nt)
#pragma unroll
        for (int kt = 0; kt < 4; ++kt)
            Bf[nt][kt] = *(const bf16x8*)(w1t + (nt * 16 + m16) * 128 + kt * 32 + quad * 8);

    // ---- Gather phase: 64 row-gathers (32 h + 32 t), 1 KB each, bf16 into LDS ----
    // 16 threads per row; per instruction a wave reads 4 contiguous 256 B chunks.
    {
        const int m = tid & 15;
#pragma unroll
        for (int r = 0; r < 4; ++r) {
            const int task = r * 16 + (tid >> 4);   // 0..63
            const int k    = task & 31;
            const int ch   = task >> 5;             // 0 = h, 1 = t
            const int idx  = triple[(ch ? tbase : hbase) + k];
            const float* __restrict__ src = node_emb + (size_t)idx * (NF * DIM);
#pragma unroll
            for (int j = 0; j < 4; ++j) {           // j = factor
                f32x4 v = *(const f32x4*)(src + j * 64 + m * 4);
                bf16x4 bv;
#pragma unroll
                for (int u = 0; u < 4; ++u) bv[u] = (__bf16)v[u];
                *(bf16x4*)(&Xs[(j * 32 + k) * XSTRIDE + ch * 64 + m * 4]) = bv;
            }
        }
    }
    __syncthreads();

    // ---- MFMA: wave w computes hid rows [w*32, w*32+32), all 64 cols ----
    f32x4 C[2][4];   // [m-tile][n-tile]
#pragma unroll
    for (int mt = 0; mt < 2; ++mt)
#pragma unroll
        for (int nt = 0; nt < 4; ++nt) C[mt][nt] = (f32x4)(0.f);

    const __bf16* Arow0 = &Xs[(w * 32 + m16) * XSTRIDE];        // m-tile 0
    const __bf16* Arow1 = &Xs[(w * 32 + 16 + m16) * XSTRIDE];   // m-tile 1
#pragma unroll
    for (int kt = 0; kt < 4; ++kt) {
        bf16x8 A0 = *(const bf16x8*)(Arow0 + kt * 32 + quad * 8);
        bf16x8 A1 = *(const bf16x8*)(Arow1 + kt * 32 + quad * 8);
#pragma unroll
        for (int nt = 0; nt < 4; ++nt) {
            C[0][nt] = __builtin_amdgcn_mfma_f32_16x16x32_bf16(A0, Bf[nt][kt], C[0][nt], 0, 0, 0);
            C[1][nt] = __builtin_amdgcn_mfma_f32_16x16x32_bf16(A1, Bf[nt][kt], C[1][nt], 0, 0, 0);
        }
    }

    // ---- Epilogue: logits[row] = sum_d relu(hid + b1) * W2  (b2 cancels in softmax) ----
    float b1v[4], w2v[4];
#pragma unroll
    for (int nt = 0; nt < 4; ++nt) {
        b1v[nt] = b1[nt * 16 + m16];
        w2v[nt] = W2[nt * 16 + m16];
    }
    float lsum[2][4];   // [mt][reg]; C row = mt*16 + quad*4 + reg, col = nt*16 + m16
#pragma unroll
    for (int mt = 0; mt < 2; ++mt)
#pragma unroll
        for (int r = 0; r < 4; ++r) {
            float s = 0.f;
#pragma unroll
            for (int nt = 0; nt < 4; ++nt)
                s += fmaxf(C[mt][nt][r] + b1v[nt], 0.f) * w2v[nt];
            lsum[mt][r] = s;
        }
    // reduce across the 16 column-lanes (lane bits 0..3)
#pragma unroll
    for (int off = 1; off < 16; off <<= 1)
#pragma unroll
        for (int mt = 0; mt < 2; ++mt)
#pragma unroll
            for (int r = 0; r < 4; ++r)
                lsum[mt][r] += __shfl_xor(lsum[mt][r], off, 64);

    if (m16 == 0) {
#pragma unroll
        for (int mt = 0; mt < 2; ++mt) {
            f32x4 v;
#pragma unroll
            for (int r = 0; r < 4; ++r) v[r] = lsum[mt][r];
            *(f32x4*)&logitS[w * 32 + mt * 16 + quad * 4] = v;
        }
    }
    __syncthreads();

    // ---- softmax over k (32 rows of this wave's factor) ----
    const float lg = logitS[w * 32 + (lane & 31)];
    float mx = lg;
#pragma unroll
    for (int off = 16; off; off >>= 1) mx = fmaxf(mx, __shfl_xor(mx, off, 64));
    const float e = __expf(lg - mx);
    float s = e;
#pragma unroll
    for (int off = 16; off; off >>= 1) s += __shfl_xor(s, off, 64);
    const float wgt = e / s;   // weight for k = lane & 31

    // ---- output: out[f][d] = sum_k w_k * t[k][f][d]  (t read back from LDS bf16) ----
    float oacc = 0.f;
#pragma unroll
    for (int k = 0; k < KK; ++k) {
        const float wk = __shfl(wgt, k, 64);
        oacc += wk * (float)Xs[(w * 32 + k) * XSTRIDE + 64 + lane];
    }
    out[(((size_t)(tower * 3 + 1 + layer) * BB + b) * NF + w) * DIM + lane] = oacc;

    // origin row (written once, by layer==0 blocks)
    if (layer == 0) {
        const int oid = idxarr[b];
        out[(((size_t)(tower * 3 + 0) * BB + b) * NF + w) * DIM + lane] =
            node_emb[((size_t)oid * NF + w) * DIM + lane];
    }
}

extern "C" void kernel_launch(void* const* d_in, const int* in_sizes, int n_in,
                              void* d_out, int out_size, void* d_ws, size_t ws_size,
                              hipStream_t stream) {
    const float* node_emb     = (const float*)d_in[0];
    // d_in[1] = relation_emb — dead in the reference computation
    const float* W1           = (const float*)d_in[2];
    const float* b1           = (const float*)d_in[3];
    const float* W2           = (const float*)d_in[4];
    const float* b2           = (const float*)d_in[5]; (void)b2; // cancels in softmax
    const int*   users        = (const int*)d_in[6];
    const int*   items        = (const int*)d_in[7];
    const int*   users_triple = (const int*)d_in[8];
    const int*   items_triple = (const int*)d_in[9];
    float* out = (float*)d_out;

    __bf16* w1t = (__bf16*)d_ws;   // 64*128*2 = 16 KB

    hipLaunchKernelGGL(prep_w1t, dim3(32), dim3(256), 0, stream, W1, w1t);
    hipLaunchKernelGGL(kgat_mfma, dim3(2 * BB * NLAYER), dim3(256), 0, stream,
                       node_emb, w1t, b1, W2,
                       users, items, users_triple, items_triple, out);
}